// Round 3
// baseline (336.000 us; speedup 1.0000x reference)
//
#include <hip/hip_runtime.h>
#include <cstdint>

#define L_SEQ 1024
#define DSRC 512
#define XPL 2097152L   // x / q / k plane stride (elems) = 2048*1024
#define WPL 1048576L   // weight plane stride = 1024*1024

typedef __attribute__((ext_vector_type(8))) short short8;
typedef __attribute__((ext_vector_type(4))) float floatx4;

__device__ __forceinline__ unsigned short f2bf(float f) {
  unsigned int x = __float_as_uint(f);
  x += 0x7fff + ((x >> 16) & 1);   // RNE
  return (unsigned short)(x >> 16);
}
__device__ __forceinline__ float bf2f(unsigned short h) {
  return __uint_as_float((unsigned)h << 16);
}
// 3-way bf16 split: f = h0 + h1 + h2 + O(2^-27 |f|)
__device__ __forceinline__ void split3(float f, unsigned short* h) {
  h[0] = f2bf(f);
  float d = f - bf2f(h[0]);
  h[1] = f2bf(d);
  h[2] = f2bf(d - bf2f(h[1]));
}

// async global->LDS, 16B per lane; dest must be the wave-uniform base
__device__ __forceinline__ void gload_lds16(const void* g, void* l) {
  __builtin_amdgcn_global_load_lds(
      (const __attribute__((address_space(1))) unsigned int*)g,
      (__attribute__((address_space(3))) unsigned int*)l, 16, 0, 0);
}

// ---------------- split the 4 fp32 inputs into 3 bf16 planes each ----------------
__global__ __launch_bounds__(256) void split_inputs_k(
    const float* __restrict__ query, const float* __restrict__ key_t,
    const float* __restrict__ wq, const float* __restrict__ wk,
    ushort* __restrict__ xs, ushort* __restrict__ wsp) {
  int blk = blockIdx.x;
  const float* in; ushort* out; long pl; int idx;
  if (blk < 2048)      { in = query; out = xs;           pl = XPL; idx = blk; }
  else if (blk < 4096) { in = key_t; out = xs + 3 * XPL; pl = XPL; idx = blk - 2048; }
  else if (blk < 5120) { in = wq;    out = wsp;          pl = WPL; idx = blk - 4096; }
  else                 { in = wk;    out = wsp + 3 * WPL; pl = WPL; idx = blk - 5120; }
  long e = (long)idx * 1024 + threadIdx.x * 4;
  float4 v = *(const float4*)(in + e);
  unsigned short h0[3], h1[3], h2[3], h3[3];
  split3(v.x, h0); split3(v.y, h1); split3(v.z, h2); split3(v.w, h3);
#pragma unroll
  for (int s = 0; s < 3; s++) {
    ushort4 u; u.x = h0[s]; u.y = h1[s]; u.z = h2[s]; u.w = h3[s];
    *(ushort4*)(out + s * pl + e) = u;
  }
}

// ---------------- projection GEMM: bf16x6 emulated fp32, global_load_lds + dbuf ----------------
// (unchanged from prior verified round)
__global__ __launch_bounds__(512, 2) void proj_gemm_k(
    const ushort* __restrict__ xs, const ushort* __restrict__ wsp,
    ushort* __restrict__ qs, ushort* __restrict__ ks,
    const float* __restrict__ bq, const float* __restrict__ bk) {
  __shared__ ushort As[2][3][4096];   // [buf][plane][row*32+col]
  __shared__ ushort Bs[2][3][4096];
  int z = blockIdx.z;
  const ushort* Ab = xs + (long)z * 3 * XPL + (long)blockIdx.y * 128 * 1024;
  const ushort* Bb = wsp + (long)z * 3 * WPL + (long)blockIdx.x * 128 * 1024;

  int tid = threadIdx.x;
  int lane = tid & 63, wv = tid >> 6;     // 8 waves
  int wm = wv >> 2, wn = wv & 3;          // wave tile: 64 rows x 32 cols
  int quad = lane >> 4, l16 = lane & 15;

  int sr = tid >> 2;                                   // row 0..127
  int scq = (((tid & 3) ^ ((sr >> 1) & 3)) << 3);      // swizzled col (ushorts)

  floatx4 acc[4][2] = {};

#pragma unroll
  for (int s = 0; s < 3; s++) {
    gload_lds16(Ab + (long)s * XPL + (long)sr * 1024 + scq, &As[0][s][wv * 512]);
    gload_lds16(Bb + (long)s * WPL + (long)sr * 1024 + scq, &Bs[0][s][wv * 512]);
  }
  __syncthreads();

  int cur = 0;
#pragma unroll 2
  for (int t = 0; t < 32; t++) {
    if (t < 31) {
      int k0 = (t + 1) * 32;
#pragma unroll
      for (int s = 0; s < 3; s++) {
        gload_lds16(Ab + (long)s * XPL + (long)sr * 1024 + k0 + scq, &As[cur ^ 1][s][wv * 512]);
        gload_lds16(Bb + (long)s * WPL + (long)sr * 1024 + k0 + scq, &Bs[cur ^ 1][s][wv * 512]);
      }
    }
    short8 af[3][4];
#pragma unroll
    for (int s = 0; s < 3; s++)
#pragma unroll
      for (int i = 0; i < 4; i++) {
        int row = wm * 64 + i * 16 + l16;
        int qa = (quad ^ ((row >> 1) & 3)) << 3;
        af[s][i] = *(const short8*)(&As[cur][s][row * 32 + qa]);
      }
#pragma unroll
    for (int j = 0; j < 2; j++) {
      int rowb = wn * 32 + j * 16 + l16;
      int boff = rowb * 32 + ((quad ^ ((rowb >> 1) & 3)) << 3);
      short8 b0 = *(const short8*)(&Bs[cur][0][boff]);
      short8 b1 = *(const short8*)(&Bs[cur][1][boff]);
      short8 b2 = *(const short8*)(&Bs[cur][2][boff]);
#pragma unroll
      for (int i = 0; i < 4; i++) {
        acc[i][j] = __builtin_amdgcn_mfma_f32_16x16x32_bf16(af[1][i], b1, acc[i][j], 0, 0, 0);
        acc[i][j] = __builtin_amdgcn_mfma_f32_16x16x32_bf16(af[0][i], b2, acc[i][j], 0, 0, 0);
        acc[i][j] = __builtin_amdgcn_mfma_f32_16x16x32_bf16(af[2][i], b0, acc[i][j], 0, 0, 0);
        acc[i][j] = __builtin_amdgcn_mfma_f32_16x16x32_bf16(af[0][i], b1, acc[i][j], 0, 0, 0);
        acc[i][j] = __builtin_amdgcn_mfma_f32_16x16x32_bf16(af[1][i], b0, acc[i][j], 0, 0, 0);
        acc[i][j] = __builtin_amdgcn_mfma_f32_16x16x32_bf16(af[0][i], b0, acc[i][j], 0, 0, 0);
      }
    }
    __syncthreads();
    cur ^= 1;
  }

  ushort* Ob = z ? ks : qs;
  const float* bias = z ? bk : bq;
#pragma unroll
  for (int j = 0; j < 2; j++) {
    int col = blockIdx.x * 128 + wn * 32 + j * 16 + l16;
    float bv = bias[col];
#pragma unroll
    for (int i = 0; i < 4; i++) {
#pragma unroll
      for (int r = 0; r < 4; r++) {
        long row = blockIdx.y * 128 + wm * 64 + i * 16 + quad * 4 + r;
        float val = acc[i][j][r] + bv;
        unsigned short h[3]; split3(val, h);
        long e = row * 1024 + col;
#pragma unroll
        for (int s = 0; s < 3; s++) Ob[s * XPL + e] = h[s];
      }
    }
  }
}

// ---------------- fused score GEMM + top-8 + softmax ----------------
// Block = 64 q-rows x 1 view x 1 batch. Grid 16x8x2 = 256 blocks = 1/CU.
// A (q panel, 3 planes, full K=128) LDS-resident; B (k panels) streamed per
// 128-col tile with double buffering. S tile kept in LDS only; running top-8
// per row held in registers (lane lc of each 8-lane row-group owns slot lc).
// Scores are bit-identical to the previous separate score kernel (same MFMA
// schedule & fragment order), so top-8 indices match exactly.
__global__ __launch_bounds__(512) void score_topk_k(
    const ushort* __restrict__ qs, const ushort* __restrict__ ks,
    float* __restrict__ wts, int* __restrict__ idxs) {
  __shared__ ushort Asm[3 * 64 * 128];       // 48 KB, [plane][row][16B-blk swz]
  __shared__ ushort Bsm[2][3 * 128 * 32];    // 2 x 24 KB
  __shared__ float  Ssm[64 * 132];           // 33 KB, padded stride 132

  // bijective XCD swizzle: each XCD owns 2 (v,b) pairs entirely (B L2-pinned)
  int fid = blockIdx.x + 16 * (blockIdx.y + 8 * blockIdx.z);
  int xcd = fid & 7, jj = fid >> 3;
  int pair = xcd * 2 + (jj & 1);
  int rt = jj >> 1;            // 0..15 row-tile
  int v = pair & 7, b = pair >> 3;

  const long arow0 = (long)b * 1024 + rt * 64;   // q-row base (in 2048-row space)
  const long brow0 = (long)b * 1024;             // key-row base
  const int vb = v * 128;

  int tid = threadIdx.x;
  int lane = tid & 63, wv = tid >> 6;
  int wm = wv >> 2, wn = wv & 3;       // wave tile 32 rows x 32 cols
  int quad = lane >> 4, l16 = lane & 15;

  // ---- A prologue: 3072 16B slots, 6 per thread, LDS-linear dest ----
#pragma unroll
  for (int n = 0; n < 6; n++) {
    int base = n * 512 + wv * 64;
    int sl = base + lane;
    int s = sl >> 10, rem = sl & 1023;
    int r = rem >> 4, sq = rem & 15;
    int qb = sq ^ (r & 7);                       // inverse swizzle on source
    gload_lds16(qs + (long)s * XPL + (arow0 + r) * 1024 + vb + qb * 8,
                &Asm[base * 8]);
  }

  // ---- B staging: 1536 slots/buffer, 3 per thread ----
  auto stageB = [&](int step, int bsel) {
    int ct2 = step >> 2, kk2 = step & 3;
    long kb = brow0 + ct2 * 128;
    int k0 = kk2 * 32;
#pragma unroll
    for (int n = 0; n < 3; n++) {
      int base = n * 512 + wv * 64;
      int sl = base + lane;
      int s = sl >> 9, rem = sl & 511;
      int c = rem >> 2, sq = rem & 3;
      int qb = sq ^ ((c >> 1) & 3);              // inverse swizzle on source
      gload_lds16(ks + (long)s * XPL + (kb + c) * 1024 + vb + k0 + qb * 8,
                  &Bsm[bsel][base * 8]);
    }
  };

  stageB(0, 0);
  __syncthreads();   // drains A + B step0

  floatx4 acc[2][2] = {};
  float rv = -1e30f; int rc = 0x7FFFFFFF;        // running top-8: lane (tid&7) owns slot (tid&7)
  const int myrow = tid >> 3, lc = tid & 7;

  int buf = 0;
  for (int ct = 0; ct < 8; ct++) {
#pragma unroll
    for (int kk = 0; kk < 4; kk++) {
      int step = ct * 4 + kk;
      if (step < 31) stageB(step + 1, buf ^ 1);

      short8 af[3][2], bf[3][2];
#pragma unroll
      for (int s = 0; s < 3; s++)
#pragma unroll
        for (int i = 0; i < 2; i++) {
          int row = wm * 32 + i * 16 + l16;
          int sqa = (kk * 4 + quad) ^ (row & 7);
          af[s][i] = *(const short8*)(&Asm[s * 8192 + row * 128 + sqa * 8]);
        }
#pragma unroll
      for (int s = 0; s < 3; s++)
#pragma unroll
        for (int j = 0; j < 2; j++) {
          int c = wn * 32 + j * 16 + l16;
          int sqb = quad ^ ((c >> 1) & 3);
          bf[s][j] = *(const short8*)(&Bsm[buf][s * 4096 + c * 32 + sqb * 8]);
        }
#pragma unroll
      for (int j = 0; j < 2; j++)
#pragma unroll
        for (int i = 0; i < 2; i++) {
          acc[i][j] = __builtin_amdgcn_mfma_f32_16x16x32_bf16(af[1][i], bf[1][j], acc[i][j], 0, 0, 0);
          acc[i][j] = __builtin_amdgcn_mfma_f32_16x16x32_bf16(af[0][i], bf[2][j], acc[i][j], 0, 0, 0);
          acc[i][j] = __builtin_amdgcn_mfma_f32_16x16x32_bf16(af[2][i], bf[0][j], acc[i][j], 0, 0, 0);
          acc[i][j] = __builtin_amdgcn_mfma_f32_16x16x32_bf16(af[0][i], bf[1][j], acc[i][j], 0, 0, 0);
          acc[i][j] = __builtin_amdgcn_mfma_f32_16x16x32_bf16(af[1][i], bf[0][j], acc[i][j], 0, 0, 0);
          acc[i][j] = __builtin_amdgcn_mfma_f32_16x16x32_bf16(af[0][i], bf[0][j], acc[i][j], 0, 0, 0);
        }
      __syncthreads();   // drains prefetch + guards buf reuse
      buf ^= 1;
    }

    // ---- tile epilogue: S -> LDS, per-row top-8, merge into running ----
#pragma unroll
    for (int i = 0; i < 2; i++)
#pragma unroll
      for (int j = 0; j < 2; j++)
#pragma unroll
        for (int r = 0; r < 4; r++) {
          int row = wm * 32 + i * 16 + quad * 4 + r;
          int col = wn * 32 + j * 16 + l16;
          Ssm[row * 132 + col] = acc[i][j][r];
          acc[i][j][r] = 0.0f;
        }
    __syncthreads();

    float vv[16];
#pragma unroll
    for (int t = 0; t < 16; t++) vv[t] = Ssm[myrow * 132 + lc + 8 * t];

    // per-tile top-8 (8 rounds); lane lc keeps round-lc winner
    float nv = -1e30f; int nc = 0x7FFFFFFF;
    for (int rd = 0; rd < 8; rd++) {
      float bv = -1e30f; int bs = 0;
#pragma unroll
      for (int t = 0; t < 16; t++)
        if (vv[t] > bv) { bv = vv[t]; bs = t; }
      int bc = ct * 128 + lc + 8 * bs;
      int myc = bc;
#pragma unroll
      for (int m = 1; m <= 4; m <<= 1) {
        float ov = __shfl_xor(bv, m);
        int oc = __shfl_xor(bc, m);
        if (ov > bv || (ov == bv && oc < bc)) { bv = ov; bc = oc; }
      }
      if (myc == bc) {                         // I own the winner: invalidate (static idx)
#pragma unroll
        for (int t = 0; t < 16; t++)
          if (t == bs) vv[t] = -1e30f;
      }
      if (lc == rd) { nv = bv; nc = bc; }
    }

    // merge running(8) + new(8) -> running(8)
    float orv = -1e30f; int orc = 0x7FFFFFFF;
    for (int rd = 0; rd < 8; rd++) {
      float bv; int bc;
      if (rv > nv || (rv == nv && rc < nc)) { bv = rv; bc = rc; }
      else { bv = nv; bc = nc; }
#pragma unroll
      for (int m = 1; m <= 4; m <<= 1) {
        float ov = __shfl_xor(bv, m);
        int oc = __shfl_xor(bc, m);
        if (ov > bv || (ov == bv && oc < bc)) { bv = ov; bc = oc; }
      }
      if (bc == rc) rv = -1e30f;
      else if (bc == nc) nv = -1e30f;
      if (lc == rd) { orv = bv; orc = bc; }
    }
    rv = orv; rc = orc;
    // next tile's S-write is >=4 barriers away -> no extra barrier needed here
  }

  // ---- softmax over the 8-lane group, write wts/idxs ----
  float mm = rv;
#pragma unroll
  for (int m = 1; m <= 4; m <<= 1) mm = fmaxf(mm, __shfl_xor(mm, m));
  float e = __expf(rv - mm);
  float sum = e;
#pragma unroll
  for (int m = 1; m <= 4; m <<= 1) sum += __shfl_xor(sum, m);
  float w = e * (1.0f / sum);

  long grow = (long)b * 8192 + v * 1024 + rt * 64 + myrow;
  wts[grow * 8 + lc] = w;
  idxs[grow * 8 + lc] = rc;
}

// ---------------- gather + weighted sum ----------------
__global__ __launch_bounds__(256) void gather_out_k(const float* __restrict__ src,
                                                    const float* __restrict__ wts,
                                                    const int* __restrict__ idxs,
                                                    float* __restrict__ out) {
  int rowid = blockIdx.x;
  int b = rowid >> 13;
  int tid = threadIdx.x;
  int d4 = tid & 127;
  int w0 = (tid >> 7) << 1;
  const float4* s4 = (const float4*)src + (long)b * (L_SEQ * (DSRC / 4));
  float wt[8]; int id[8];
#pragma unroll
  for (int k = 0; k < 8; k++) {
    wt[k] = wts[(long)rowid * 8 + k];
    id[k] = idxs[(long)rowid * 8 + k];
  }
  float ax = 0, ay = 0, az = 0, aw = 0;
  float bx = 0, by = 0, bz2 = 0, bw = 0;
#pragma unroll
  for (int k = 0; k < 8; k++) {
    int r0 = id[k] + w0 - 1;
    if ((unsigned)r0 < (unsigned)L_SEQ) {
      float4 x = s4[(long)r0 * 128 + d4];
      ax += wt[k] * x.x; ay += wt[k] * x.y; az += wt[k] * x.z; aw += wt[k] * x.w;
    }
    int r1 = r0 + 1;
    if ((unsigned)r1 < (unsigned)L_SEQ) {
      float4 x = s4[(long)r1 * 128 + d4];
      bx += wt[k] * x.x; by += wt[k] * x.y; bz2 += wt[k] * x.z; bw += wt[k] * x.w;
    }
  }
  float4* o4 = (float4*)out + ((long)rowid * 4 + w0) * 128 + d4;
  o4[0] = make_float4(ax, ay, az, aw);
  o4[128] = make_float4(bx, by, bz2, bw);
}

extern "C" void kernel_launch(void* const* d_in, const int* in_sizes, int n_in,
                              void* d_out, int out_size, void* d_ws, size_t ws_size,
                              hipStream_t stream) {
  (void)in_sizes; (void)n_in; (void)out_size; (void)ws_size;
  const float* query  = (const float*)d_in[0];
  const float* key_t  = (const float*)d_in[1];
  const float* source = (const float*)d_in[2];
  const float* wq     = (const float*)d_in[3];
  const float* bq     = (const float*)d_in[4];
  const float* wk     = (const float*)d_in[5];
  const float* bk     = (const float*)d_in[6];

  char* ws = (char*)d_ws;
  // ws layout (bytes), max end 63,963,136 < proven 84,934,656:
  //   0         qs  bf16x3 planes of q (3 x 2048x1024)  12.58 MB  live: proj -> score
  //   12582912  ks  bf16x3 planes of k                  12.58 MB
  //   25165824  wts fp32 (16384x8)                      512 KB
  //   25690112  idxs i32                                512 KB
  //   26214400  xs: 6 bf16 planes (xq,xk)               25.17 MB  dead after proj
  //   51380224  wsp: 6 bf16 planes (wq,wk)              12.58 MB  dead after proj
  //   (scores never materialized in global memory anymore)
  ushort* qs  = (ushort*)(ws);
  ushort* ksp = (ushort*)(ws + 12582912);
  float*  wts = (float*)(ws + 25165824);
  int*    idxs= (int*)(ws + 25690112);
  ushort* xs  = (ushort*)(ws + 26214400);
  ushort* wsp = (ushort*)(ws + 51380224);

  split_inputs_k<<<6144, 256, 0, stream>>>(query, key_t, wq, wk, xs, wsp);
  proj_gemm_k<<<dim3(8, 16, 2), 512, 0, stream>>>(xs, wsp, qs, ksp, bq, bk);
  score_topk_k<<<dim3(16, 8, 2), 512, 0, stream>>>(qs, ksp, wts, idxs);
  gather_out_k<<<16384, 256, 0, stream>>>(source, wts, idxs, (float*)d_out);
}

// Round 4
// 322.984 us; speedup vs baseline: 1.0403x; 1.0403x over previous
//
#include <hip/hip_runtime.h>
#include <cstdint>

#define L_SEQ 1024
#define DSRC 512
#define XPL 2097152L   // x / q / k plane stride (elems) = 2048*1024
#define WPL 1048576L   // weight plane stride = 1024*1024

typedef __attribute__((ext_vector_type(8))) short short8;
typedef __attribute__((ext_vector_type(4))) float floatx4;

__device__ __forceinline__ unsigned short f2bf(float f) {
  unsigned int x = __float_as_uint(f);
  x += 0x7fff + ((x >> 16) & 1);   // RNE
  return (unsigned short)(x >> 16);
}
__device__ __forceinline__ float bf2f(unsigned short h) {
  return __uint_as_float((unsigned)h << 16);
}
// 3-way bf16 split: f = h0 + h1 + h2 + O(2^-27 |f|)
__device__ __forceinline__ void split3(float f, unsigned short* h) {
  h[0] = f2bf(f);
  float d = f - bf2f(h[0]);
  h[1] = f2bf(d);
  h[2] = f2bf(d - bf2f(h[1]));
}

// async global->LDS, 16B per lane; dest must be the wave-uniform base
__device__ __forceinline__ void gload_lds16(const void* g, void* l) {
  __builtin_amdgcn_global_load_lds(
      (const __attribute__((address_space(1))) unsigned int*)g,
      (__attribute__((address_space(3))) unsigned int*)l, 16, 0, 0);
}

// total order for top-k: value desc, index asc (matches jax.lax.top_k ties)
__device__ __forceinline__ bool better(float av, int ac, float bv, int bc) {
  return av > bv || (av == bv && ac < bc);
}
// insert (v,c) into desc-sorted 8-list; static indexing only (regs, no scratch)
__device__ __forceinline__ void ins8(float (&tv)[8], int (&ti)[8], float v, int c) {
  if (better(v, c, tv[7], ti[7])) {
    tv[7] = v; ti[7] = c;
#pragma unroll
    for (int s = 7; s > 0; s--)
      if (better(tv[s], ti[s], tv[s - 1], ti[s - 1])) {
        float a = tv[s]; tv[s] = tv[s - 1]; tv[s - 1] = a;
        int b2 = ti[s]; ti[s] = ti[s - 1]; ti[s - 1] = b2;
      }
  }
}
// merge sorted 8-lists of the 4 quad-lanes (xor 16/32) -> quad0 lane stores
// the group's top-8 (desc) to LDS at base. k-indices are disjoint across lanes.
__device__ __forceinline__ void quadmerge_store(float (&tv)[8], int (&ti)[8],
                                                float* Mv, int* Mi, int base, int quad) {
#pragma unroll
  for (int t = 0; t < 8; t++) {
    float bv = tv[0]; int bc = ti[0];
    float ov = __shfl_xor(bv, 16); int oc = __shfl_xor(bc, 16);
    if (better(ov, oc, bv, bc)) { bv = ov; bc = oc; }
    ov = __shfl_xor(bv, 32); oc = __shfl_xor(bc, 32);
    if (better(ov, oc, bv, bc)) { bv = ov; bc = oc; }
    if (bc == ti[0]) {   // I own the winner: pop (shift, static idx)
#pragma unroll
      for (int s = 0; s < 7; s++) { tv[s] = tv[s + 1]; ti[s] = ti[s + 1]; }
      tv[7] = -1e30f; ti[7] = 0x7FFFFFFF;
    }
    if (quad == 0) { Mv[base + t] = bv; Mi[base + t] = bc; }
  }
}

// ---------------- split the 4 fp32 inputs into 3 bf16 planes each ----------------
__global__ __launch_bounds__(256) void split_inputs_k(
    const float* __restrict__ query, const float* __restrict__ key_t,
    const float* __restrict__ wq, const float* __restrict__ wk,
    ushort* __restrict__ xs, ushort* __restrict__ wsp) {
  int blk = blockIdx.x;
  const float* in; ushort* out; long pl; int idx;
  if (blk < 2048)      { in = query; out = xs;           pl = XPL; idx = blk; }
  else if (blk < 4096) { in = key_t; out = xs + 3 * XPL; pl = XPL; idx = blk - 2048; }
  else if (blk < 5120) { in = wq;    out = wsp;          pl = WPL; idx = blk - 4096; }
  else                 { in = wk;    out = wsp + 3 * WPL; pl = WPL; idx = blk - 5120; }
  long e = (long)idx * 1024 + threadIdx.x * 4;
  float4 v = *(const float4*)(in + e);
  unsigned short h0[3], h1[3], h2[3], h3[3];
  split3(v.x, h0); split3(v.y, h1); split3(v.z, h2); split3(v.w, h3);
#pragma unroll
  for (int s = 0; s < 3; s++) {
    ushort4 u; u.x = h0[s]; u.y = h1[s]; u.z = h2[s]; u.w = h3[s];
    *(ushort4*)(out + s * pl + e) = u;
  }
}

// ---------------- projection GEMM: bf16x6 emulated fp32, global_load_lds + dbuf ----------------
// (unchanged from prior verified round)
__global__ __launch_bounds__(512, 2) void proj_gemm_k(
    const ushort* __restrict__ xs, const ushort* __restrict__ wsp,
    ushort* __restrict__ qs, ushort* __restrict__ ks,
    const float* __restrict__ bq, const float* __restrict__ bk) {
  __shared__ ushort As[2][3][4096];   // [buf][plane][row*32+col]
  __shared__ ushort Bs[2][3][4096];
  int z = blockIdx.z;
  const ushort* Ab = xs + (long)z * 3 * XPL + (long)blockIdx.y * 128 * 1024;
  const ushort* Bb = wsp + (long)z * 3 * WPL + (long)blockIdx.x * 128 * 1024;

  int tid = threadIdx.x;
  int lane = tid & 63, wv = tid >> 6;     // 8 waves
  int wm = wv >> 2, wn = wv & 3;          // wave tile: 64 rows x 32 cols
  int quad = lane >> 4, l16 = lane & 15;

  int sr = tid >> 2;                                   // row 0..127
  int scq = (((tid & 3) ^ ((sr >> 1) & 3)) << 3);      // swizzled col (ushorts)

  floatx4 acc[4][2] = {};

#pragma unroll
  for (int s = 0; s < 3; s++) {
    gload_lds16(Ab + (long)s * XPL + (long)sr * 1024 + scq, &As[0][s][wv * 512]);
    gload_lds16(Bb + (long)s * WPL + (long)sr * 1024 + scq, &Bs[0][s][wv * 512]);
  }
  __syncthreads();

  int cur = 0;
#pragma unroll 2
  for (int t = 0; t < 32; t++) {
    if (t < 31) {
      int k0 = (t + 1) * 32;
#pragma unroll
      for (int s = 0; s < 3; s++) {
        gload_lds16(Ab + (long)s * XPL + (long)sr * 1024 + k0 + scq, &As[cur ^ 1][s][wv * 512]);
        gload_lds16(Bb + (long)s * WPL + (long)sr * 1024 + k0 + scq, &Bs[cur ^ 1][s][wv * 512]);
      }
    }
    short8 af[3][4];
#pragma unroll
    for (int s = 0; s < 3; s++)
#pragma unroll
      for (int i = 0; i < 4; i++) {
        int row = wm * 64 + i * 16 + l16;
        int qa = (quad ^ ((row >> 1) & 3)) << 3;
        af[s][i] = *(const short8*)(&As[cur][s][row * 32 + qa]);
      }
#pragma unroll
    for (int j = 0; j < 2; j++) {
      int rowb = wn * 32 + j * 16 + l16;
      int boff = rowb * 32 + ((quad ^ ((rowb >> 1) & 3)) << 3);
      short8 b0 = *(const short8*)(&Bs[cur][0][boff]);
      short8 b1 = *(const short8*)(&Bs[cur][1][boff]);
      short8 b2 = *(const short8*)(&Bs[cur][2][boff]);
#pragma unroll
      for (int i = 0; i < 4; i++) {
        acc[i][j] = __builtin_amdgcn_mfma_f32_16x16x32_bf16(af[1][i], b1, acc[i][j], 0, 0, 0);
        acc[i][j] = __builtin_amdgcn_mfma_f32_16x16x32_bf16(af[0][i], b2, acc[i][j], 0, 0, 0);
        acc[i][j] = __builtin_amdgcn_mfma_f32_16x16x32_bf16(af[2][i], b0, acc[i][j], 0, 0, 0);
        acc[i][j] = __builtin_amdgcn_mfma_f32_16x16x32_bf16(af[0][i], b1, acc[i][j], 0, 0, 0);
        acc[i][j] = __builtin_amdgcn_mfma_f32_16x16x32_bf16(af[1][i], b0, acc[i][j], 0, 0, 0);
        acc[i][j] = __builtin_amdgcn_mfma_f32_16x16x32_bf16(af[0][i], b0, acc[i][j], 0, 0, 0);
      }
    }
    __syncthreads();
    cur ^= 1;
  }

  ushort* Ob = z ? ks : qs;
  const float* bias = z ? bk : bq;
#pragma unroll
  for (int j = 0; j < 2; j++) {
    int col = blockIdx.x * 128 + wn * 32 + j * 16 + l16;
    float bv = bias[col];
#pragma unroll
    for (int i = 0; i < 4; i++) {
#pragma unroll
      for (int r = 0; r < 4; r++) {
        long row = blockIdx.y * 128 + wm * 64 + i * 16 + quad * 4 + r;
        float val = acc[i][j][r] + bv;
        unsigned short h[3]; split3(val, h);
        long e = row * 1024 + col;
#pragma unroll
        for (int s = 0; s < 3; s++) Ob[s * XPL + e] = h[s];
      }
    }
  }
}

// ---------------- fused score GEMM + top-8 + softmax (swapped operands) ----------------
// Computes T = K*Q^T per tile: output col = l16 = q-row, row = k-index -> each
// lane holds k-scores for 2 q-rows only. Top-8 = per-lane register insertion
// (no LDS round-trip, no per-tile barriers/serial phases), one quad-merge per
// wave + tiny cross-wave LDS merge at the end. Scores bit-identical to the
// non-swapped version: same product multiset, same k-order adder tree, same
// 6-term plane schedule, same tile-k order.
__global__ __launch_bounds__(512, 2) void score_topk_k(
    const ushort* __restrict__ qs, const ushort* __restrict__ ks,
    float* __restrict__ wts, int* __restrict__ idxs) {
  __shared__ __align__(16) ushort smem[49152];   // 96 KB
  ushort* Qsm = smem;                      // 3 planes x 64 rows x 128 = 24576
  ushort* Kb0 = smem + 24576;              // 2 bufs x (3 x 128 x 32) = 24576
  float* Mv = (float*)(smem + 24576);      // overlay on K region (dead at end)
  int*   Mi = (int*)(smem + 24576 + 4096); // 4 waves x 64 q x 8

  // bijective XCD swizzle: each XCD owns 2 (v,b) pairs entirely (K L2-pinned)
  int fid = blockIdx.x + 16 * (blockIdx.y + 8 * blockIdx.z);
  int xcd = fid & 7, jj = fid >> 3;
  int pair = xcd * 2 + (jj & 1);
  int rt = jj >> 1;            // 0..15 q row-tile
  int v = pair & 7, b = pair >> 3;

  const long arow0 = (long)b * 1024 + rt * 64;   // q-row base (2048-row space)
  const long brow0 = (long)b * 1024;             // key-row base
  const int vb = v * 128;

  int tid = threadIdx.x;
  int lane = tid & 63, wv = tid >> 6;
  int kg = wv & 3, qg = wv >> 2;       // wave: 32 k-rows x 32 q-cols of tile
  int quad = lane >> 4, l16 = lane & 15;

  // ---- Q prologue: 3072 16B slots, 6 per thread, LDS-linear dest ----
#pragma unroll
  for (int n = 0; n < 6; n++) {
    int base = n * 512 + wv * 64;
    int sl = base + lane;
    int s = sl >> 10, rem = sl & 1023;
    int r = rem >> 4, sq = rem & 15;
    int qb = sq ^ (r & 7);                       // inverse swizzle on source
    gload_lds16(qs + (long)s * XPL + (arow0 + r) * 1024 + vb + qb * 8,
                &Qsm[base * 8]);
  }

  // ---- K staging: 1536 slots/buffer, 3 per thread ----
  auto stageK = [&](int step, int bsel) {
    int ct2 = step >> 2, kk2 = step & 3;
    long kb = brow0 + ct2 * 128;
    int k0 = kk2 * 32;
    ushort* Kd = Kb0 + bsel * 12288;
#pragma unroll
    for (int n = 0; n < 3; n++) {
      int base = n * 512 + wv * 64;
      int sl = base + lane;
      int s = sl >> 9, rem = sl & 511;
      int c = rem >> 2, sq = rem & 3;
      int qb = sq ^ ((c >> 1) & 3);              // inverse swizzle on source
      gload_lds16(ks + (long)s * XPL + (kb + c) * 1024 + vb + k0 + qb * 8,
                  &Kd[base * 8]);
    }
  };

  stageK(0, 0);
  __syncthreads();   // drains Q + K step0

  floatx4 acc[2][2] = {};                // [i: k 16-group][j: q 16-group]
  float tv0[8], tv1[8]; int ti0[8], ti1[8];   // per-lane top-8, rows j=0 / j=1
#pragma unroll
  for (int t = 0; t < 8; t++) {
    tv0[t] = tv1[t] = -1e30f; ti0[t] = ti1[t] = 0x7FFFFFFF;
  }

  int buf = 0;
  for (int ct = 0; ct < 8; ct++) {
#pragma unroll
    for (int kk = 0; kk < 4; kk++) {
      int step = ct * 4 + kk;
      if (step < 31) stageK(step + 1, buf ^ 1);

      const ushort* Kc = Kb0 + buf * 12288;
      short8 qf[3][2], kf[3][2];
#pragma unroll
      for (int s = 0; s < 3; s++)
#pragma unroll
        for (int j = 0; j < 2; j++) {
          int q = qg * 32 + j * 16 + l16;
          int sqa = (kk * 4 + quad) ^ (q & 7);
          qf[s][j] = *(const short8*)(&Qsm[s * 8192 + q * 128 + sqa * 8]);
        }
#pragma unroll
      for (int s = 0; s < 3; s++)
#pragma unroll
        for (int i = 0; i < 2; i++) {
          int c = kg * 32 + i * 16 + l16;
          int sqb = quad ^ ((c >> 1) & 3);
          kf[s][i] = *(const short8*)(&Kc[s * 4096 + c * 32 + sqb * 8]);
        }
#pragma unroll
      for (int j = 0; j < 2; j++)
#pragma unroll
        for (int i = 0; i < 2; i++) {
          // same (qplane,kplane) order as before: (1,1),(0,2),(2,0),(0,1),(1,0),(0,0)
          acc[i][j] = __builtin_amdgcn_mfma_f32_16x16x32_bf16(kf[1][i], qf[1][j], acc[i][j], 0, 0, 0);
          acc[i][j] = __builtin_amdgcn_mfma_f32_16x16x32_bf16(kf[2][i], qf[0][j], acc[i][j], 0, 0, 0);
          acc[i][j] = __builtin_amdgcn_mfma_f32_16x16x32_bf16(kf[0][i], qf[2][j], acc[i][j], 0, 0, 0);
          acc[i][j] = __builtin_amdgcn_mfma_f32_16x16x32_bf16(kf[1][i], qf[0][j], acc[i][j], 0, 0, 0);
          acc[i][j] = __builtin_amdgcn_mfma_f32_16x16x32_bf16(kf[0][i], qf[1][j], acc[i][j], 0, 0, 0);
          acc[i][j] = __builtin_amdgcn_mfma_f32_16x16x32_bf16(kf[0][i], qf[0][j], acc[i][j], 0, 0, 0);
        }
      __syncthreads();   // drains prefetch + guards buf reuse
      buf ^= 1;
    }

    // ---- register-only top-8 insertion for this tile's 16 values ----
#pragma unroll
    for (int i = 0; i < 2; i++)
#pragma unroll
      for (int r = 0; r < 4; r++) {
        int kglob = ct * 128 + kg * 32 + i * 16 + quad * 4 + r;
        ins8(tv0, ti0, acc[i][0][r], kglob);
        ins8(tv1, ti1, acc[i][1][r], kglob);
        acc[i][0][r] = 0.0f; acc[i][1][r] = 0.0f;
      }
  }

  // ---- merge across the 4 quad-lanes; quad0 stores per-wave list to LDS ----
  // (K buffers dead: all waves passed the final barrier before any Mv write)
  int q0 = qg * 32 + l16;
  quadmerge_store(tv0, ti0, Mv, Mi, (kg * 64 + q0) * 8, quad);
  int q1 = q0 + 16;
  quadmerge_store(tv1, ti1, Mv, Mi, (kg * 64 + q1) * 8, quad);
  __syncthreads();

  // ---- final 4-list merge + softmax, one thread per q-row ----
  if (tid < 64) {
    int q = tid;
    int i0 = 0, i1 = 0, i2 = 0, i3 = 0;
    float pv[8]; int pc[8];
#pragma unroll
    for (int t = 0; t < 8; t++) {
      float v0 = Mv[(0 * 64 + q) * 8 + i0]; int c0 = Mi[(0 * 64 + q) * 8 + i0];
      float v1 = Mv[(1 * 64 + q) * 8 + i1]; int c1 = Mi[(1 * 64 + q) * 8 + i1];
      float v2 = Mv[(2 * 64 + q) * 8 + i2]; int c2 = Mi[(2 * 64 + q) * 8 + i2];
      float v3 = Mv[(3 * 64 + q) * 8 + i3]; int c3 = Mi[(3 * 64 + q) * 8 + i3];
      bool b01 = better(v1, c1, v0, c0);
      float w01v = b01 ? v1 : v0; int w01c = b01 ? c1 : c0; int w01l = b01 ? 1 : 0;
      bool b23 = better(v3, c3, v2, c2);
      float w23v = b23 ? v3 : v2; int w23c = b23 ? c3 : c2; int w23l = b23 ? 3 : 2;
      bool bf_ = better(w23v, w23c, w01v, w01c);
      float wvv = bf_ ? w23v : w01v; int wcc = bf_ ? w23c : w01c;
      int wl = bf_ ? w23l : w01l;
      i0 += (wl == 0); i1 += (wl == 1); i2 += (wl == 2); i3 += (wl == 3);
      pv[t] = wvv; pc[t] = wcc;
    }
    float m = pv[0], sum = 0.f, e[8];
#pragma unroll
    for (int t = 0; t < 8; t++) { e[t] = __expf(pv[t] - m); sum += e[t]; }
    float inv = 1.0f / sum;
    long grow = (long)b * 8192 + v * 1024 + rt * 64 + q;
#pragma unroll
    for (int t = 0; t < 8; t++) {
      wts[grow * 8 + t] = e[t] * inv;
      idxs[grow * 8 + t] = pc[t];
    }
  }
}

// ---------------- gather + weighted sum ----------------
__global__ __launch_bounds__(256) void gather_out_k(const float* __restrict__ src,
                                                    const float* __restrict__ wts,
                                                    const int* __restrict__ idxs,
                                                    float* __restrict__ out) {
  int rowid = blockIdx.x;
  int b = rowid >> 13;
  int tid = threadIdx.x;
  int d4 = tid & 127;
  int w0 = (tid >> 7) << 1;
  const float4* s4 = (const float4*)src + (long)b * (L_SEQ * (DSRC / 4));
  float wt[8]; int id[8];
#pragma unroll
  for (int k = 0; k < 8; k++) {
    wt[k] = wts[(long)rowid * 8 + k];
    id[k] = idxs[(long)rowid * 8 + k];
  }
  float ax = 0, ay = 0, az = 0, aw = 0;
  float bx = 0, by = 0, bz2 = 0, bw = 0;
#pragma unroll
  for (int k = 0; k < 8; k++) {
    int r0 = id[k] + w0 - 1;
    if ((unsigned)r0 < (unsigned)L_SEQ) {
      float4 x = s4[(long)r0 * 128 + d4];
      ax += wt[k] * x.x; ay += wt[k] * x.y; az += wt[k] * x.z; aw += wt[k] * x.w;
    }
    int r1 = r0 + 1;
    if ((unsigned)r1 < (unsigned)L_SEQ) {
      float4 x = s4[(long)r1 * 128 + d4];
      bx += wt[k] * x.x; by += wt[k] * x.y; bz2 += wt[k] * x.z; bw += wt[k] * x.w;
    }
  }
  float4* o4 = (float4*)out + ((long)rowid * 4 + w0) * 128 + d4;
  o4[0] = make_float4(ax, ay, az, aw);
  o4[128] = make_float4(bx, by, bz2, bw);
}

extern "C" void kernel_launch(void* const* d_in, const int* in_sizes, int n_in,
                              void* d_out, int out_size, void* d_ws, size_t ws_size,
                              hipStream_t stream) {
  (void)in_sizes; (void)n_in; (void)out_size; (void)ws_size;
  const float* query  = (const float*)d_in[0];
  const float* key_t  = (const float*)d_in[1];
  const float* source = (const float*)d_in[2];
  const float* wq     = (const float*)d_in[3];
  const float* bq     = (const float*)d_in[4];
  const float* wk     = (const float*)d_in[5];
  const float* bk     = (const float*)d_in[6];

  char* ws = (char*)d_ws;
  // ws layout (bytes), max end 63,963,136 < proven 84,934,656:
  //   0         qs  bf16x3 planes of q (3 x 2048x1024)  12.58 MB  live: proj -> score
  //   12582912  ks  bf16x3 planes of k                  12.58 MB
  //   25165824  wts fp32 (16384x8)                      512 KB
  //   25690112  idxs i32                                512 KB
  //   26214400  xs: 6 bf16 planes (xq,xk)               25.17 MB  dead after proj
  //   51380224  wsp: 6 bf16 planes (wq,wk)              12.58 MB  dead after proj
  //   (scores never materialized in global memory)
  ushort* qs  = (ushort*)(ws);
  ushort* ksp = (ushort*)(ws + 12582912);
  float*  wts = (float*)(ws + 25165824);
  int*    idxs= (int*)(ws + 25690112);
  ushort* xs  = (ushort*)(ws + 26214400);
  ushort* wsp = (ushort*)(ws + 51380224);

  split_inputs_k<<<6144, 256, 0, stream>>>(query, key_t, wq, wk, xs, wsp);
  proj_gemm_k<<<dim3(8, 16, 2), 512, 0, stream>>>(xs, wsp, qs, ksp, bq, bk);
  score_topk_k<<<dim3(16, 8, 2), 512, 0, stream>>>(qs, ksp, wts, idxs);
  gather_out_k<<<16384, 256, 0, stream>>>(source, wts, idxs, (float*)d_out);
}

// Round 5
// 289.757 us; speedup vs baseline: 1.1596x; 1.1147x over previous
//
#include <hip/hip_runtime.h>
#include <cstdint>

#define L_SEQ 1024
#define DSRC 512
#define XPL 2097152L   // x / q / k plane stride (elems) = 2048*1024
#define WPL 1048576L   // weight plane stride = 1024*1024

typedef __attribute__((ext_vector_type(8))) short short8;
typedef __attribute__((ext_vector_type(4))) float floatx4;

__device__ __forceinline__ unsigned short f2bf(float f) {
  unsigned int x = __float_as_uint(f);
  x += 0x7fff + ((x >> 16) & 1);   // RNE
  return (unsigned short)(x >> 16);
}
__device__ __forceinline__ float bf2f(unsigned short h) {
  return __uint_as_float((unsigned)h << 16);
}
// 3-way bf16 split: f = h0 + h1 + h2 + O(2^-27 |f|)
__device__ __forceinline__ void split3(float f, unsigned short* h) {
  h[0] = f2bf(f);
  float d = f - bf2f(h[0]);
  h[1] = f2bf(d);
  h[2] = f2bf(d - bf2f(h[1]));
}

// async global->LDS, 16B per lane; dest must be the wave-uniform base
__device__ __forceinline__ void gload_lds16(const void* g, void* l) {
  __builtin_amdgcn_global_load_lds(
      (const __attribute__((address_space(1))) unsigned int*)g,
      (__attribute__((address_space(3))) unsigned int*)l, 16, 0, 0);
}

// total order for top-k: value desc, index asc (matches jax.lax.top_k ties)
__device__ __forceinline__ bool better(float av, int ac, float bv, int bc) {
  return av > bv || (av == bv && ac < bc);
}
// float-only STABLE insertion into desc-sorted 8-list. Valid because each
// lane's candidates arrive in strictly ascending k: strict '>' displacement
// makes equal values keep the earlier (smaller) index -> identical selection
// to the explicit (val desc, idx asc) comparator, at half the VALU cost.
__device__ __forceinline__ void ins8f(float (&tv)[8], int (&ti)[8], float v, int c) {
  if (v > tv[7]) {
    tv[7] = v; ti[7] = c;
#pragma unroll
    for (int s = 7; s > 0; s--) {
      float x = tv[s], y = tv[s - 1];
      int xi = ti[s], yi = ti[s - 1];
      bool sw = x > y;                 // strict: stability preserved
      tv[s] = sw ? y : x;     tv[s - 1] = sw ? x : y;
      ti[s] = sw ? yi : xi;   ti[s - 1] = sw ? xi : yi;
    }
  }
}
// merge sorted 8-lists of the 4 quad-lanes (xor 16/32) -> quad0 lane stores
// the group's top-8 (desc) to LDS at base. k-indices are disjoint across lanes.
__device__ __forceinline__ void quadmerge_store(float (&tv)[8], int (&ti)[8],
                                                float* Mv, int* Mi, int base, int quad) {
#pragma unroll
  for (int t = 0; t < 8; t++) {
    float bv = tv[0]; int bc = ti[0];
    float ov = __shfl_xor(bv, 16); int oc = __shfl_xor(bc, 16);
    if (better(ov, oc, bv, bc)) { bv = ov; bc = oc; }
    ov = __shfl_xor(bv, 32); oc = __shfl_xor(bc, 32);
    if (better(ov, oc, bv, bc)) { bv = ov; bc = oc; }
    if (bc == ti[0]) {   // I own the winner: pop (shift, static idx)
#pragma unroll
      for (int s = 0; s < 7; s++) { tv[s] = tv[s + 1]; ti[s] = ti[s + 1]; }
      tv[7] = -1e30f; ti[7] = 0x7FFFFFFF;
    }
    if (quad == 0) { Mv[base + t] = bv; Mi[base + t] = bc; }
  }
}

// ---------------- split the 4 fp32 inputs into 3 bf16 planes each ----------------
__global__ __launch_bounds__(256) void split_inputs_k(
    const float* __restrict__ query, const float* __restrict__ key_t,
    const float* __restrict__ wq, const float* __restrict__ wk,
    ushort* __restrict__ xs, ushort* __restrict__ wsp) {
  int blk = blockIdx.x;
  const float* in; ushort* out; long pl; int idx;
  if (blk < 2048)      { in = query; out = xs;           pl = XPL; idx = blk; }
  else if (blk < 4096) { in = key_t; out = xs + 3 * XPL; pl = XPL; idx = blk - 2048; }
  else if (blk < 5120) { in = wq;    out = wsp;          pl = WPL; idx = blk - 4096; }
  else                 { in = wk;    out = wsp + 3 * WPL; pl = WPL; idx = blk - 5120; }
  long e = (long)idx * 1024 + threadIdx.x * 4;
  float4 v = *(const float4*)(in + e);
  unsigned short h0[3], h1[3], h2[3], h3[3];
  split3(v.x, h0); split3(v.y, h1); split3(v.z, h2); split3(v.w, h3);
#pragma unroll
  for (int s = 0; s < 3; s++) {
    ushort4 u; u.x = h0[s]; u.y = h1[s]; u.z = h2[s]; u.w = h3[s];
    *(ushort4*)(out + s * pl + e) = u;
  }
}

// ---------------- projection GEMM: bf16x6 emulated fp32, global_load_lds + dbuf ----------------
// (unchanged from prior verified round)
__global__ __launch_bounds__(512, 2) void proj_gemm_k(
    const ushort* __restrict__ xs, const ushort* __restrict__ wsp,
    ushort* __restrict__ qs, ushort* __restrict__ ks,
    const float* __restrict__ bq, const float* __restrict__ bk) {
  __shared__ ushort As[2][3][4096];   // [buf][plane][row*32+col]
  __shared__ ushort Bs[2][3][4096];
  int z = blockIdx.z;
  const ushort* Ab = xs + (long)z * 3 * XPL + (long)blockIdx.y * 128 * 1024;
  const ushort* Bb = wsp + (long)z * 3 * WPL + (long)blockIdx.x * 128 * 1024;

  int tid = threadIdx.x;
  int lane = tid & 63, wv = tid >> 6;     // 8 waves
  int wm = wv >> 2, wn = wv & 3;          // wave tile: 64 rows x 32 cols
  int quad = lane >> 4, l16 = lane & 15;

  int sr = tid >> 2;                                   // row 0..127
  int scq = (((tid & 3) ^ ((sr >> 1) & 3)) << 3);      // swizzled col (ushorts)

  floatx4 acc[4][2] = {};

#pragma unroll
  for (int s = 0; s < 3; s++) {
    gload_lds16(Ab + (long)s * XPL + (long)sr * 1024 + scq, &As[0][s][wv * 512]);
    gload_lds16(Bb + (long)s * WPL + (long)sr * 1024 + scq, &Bs[0][s][wv * 512]);
  }
  __syncthreads();

  int cur = 0;
#pragma unroll 2
  for (int t = 0; t < 32; t++) {
    if (t < 31) {
      int k0 = (t + 1) * 32;
#pragma unroll
      for (int s = 0; s < 3; s++) {
        gload_lds16(Ab + (long)s * XPL + (long)sr * 1024 + k0 + scq, &As[cur ^ 1][s][wv * 512]);
        gload_lds16(Bb + (long)s * WPL + (long)sr * 1024 + k0 + scq, &Bs[cur ^ 1][s][wv * 512]);
      }
    }
    short8 af[3][4];
#pragma unroll
    for (int s = 0; s < 3; s++)
#pragma unroll
      for (int i = 0; i < 4; i++) {
        int row = wm * 64 + i * 16 + l16;
        int qa = (quad ^ ((row >> 1) & 3)) << 3;
        af[s][i] = *(const short8*)(&As[cur][s][row * 32 + qa]);
      }
#pragma unroll
    for (int j = 0; j < 2; j++) {
      int rowb = wn * 32 + j * 16 + l16;
      int boff = rowb * 32 + ((quad ^ ((rowb >> 1) & 3)) << 3);
      short8 b0 = *(const short8*)(&Bs[cur][0][boff]);
      short8 b1 = *(const short8*)(&Bs[cur][1][boff]);
      short8 b2 = *(const short8*)(&Bs[cur][2][boff]);
#pragma unroll
      for (int i = 0; i < 4; i++) {
        acc[i][j] = __builtin_amdgcn_mfma_f32_16x16x32_bf16(af[1][i], b1, acc[i][j], 0, 0, 0);
        acc[i][j] = __builtin_amdgcn_mfma_f32_16x16x32_bf16(af[0][i], b2, acc[i][j], 0, 0, 0);
        acc[i][j] = __builtin_amdgcn_mfma_f32_16x16x32_bf16(af[2][i], b0, acc[i][j], 0, 0, 0);
        acc[i][j] = __builtin_amdgcn_mfma_f32_16x16x32_bf16(af[0][i], b1, acc[i][j], 0, 0, 0);
        acc[i][j] = __builtin_amdgcn_mfma_f32_16x16x32_bf16(af[1][i], b0, acc[i][j], 0, 0, 0);
        acc[i][j] = __builtin_amdgcn_mfma_f32_16x16x32_bf16(af[0][i], b0, acc[i][j], 0, 0, 0);
      }
    }
    __syncthreads();
    cur ^= 1;
  }

  ushort* Ob = z ? ks : qs;
  const float* bias = z ? bk : bq;
#pragma unroll
  for (int j = 0; j < 2; j++) {
    int col = blockIdx.x * 128 + wn * 32 + j * 16 + l16;
    float bv = bias[col];
#pragma unroll
    for (int i = 0; i < 4; i++) {
#pragma unroll
      for (int r = 0; r < 4; r++) {
        long row = blockIdx.y * 128 + wm * 64 + i * 16 + quad * 4 + r;
        float val = acc[i][j][r] + bv;
        unsigned short h[3]; split3(val, h);
        long e = row * 1024 + col;
#pragma unroll
        for (int s = 0; s < 3; s++) Ob[s * XPL + e] = h[s];
      }
    }
  }
}

// ---------------- fused score GEMM + top-8 + softmax (swapped operands) ----------------
// Block = 32 q-rows x 1 view x 1 batch, 512 threads, LDS 72KB -> 2 blocks/CU
// (cross-block MFMA/VALU overlap). Each lane owns ONE q-row's candidates.
// T15-style pipeline: tile ct's candidates held in pend regs and inserted
// during tile ct+1's MFMA phases. Scores & selection bit-identical to the
// verified round-4 kernel (same MFMA schedule/order, stable insertion).
__global__ __launch_bounds__(512, 4) void score_topk_k(
    const ushort* __restrict__ qs, const ushort* __restrict__ ks,
    float* __restrict__ wts, int* __restrict__ idxs) {
  __shared__ __align__(16) ushort smem[36864];   // 72 KB
  ushort* Qsm = smem;                      // 3 planes x 32 rows x 128 = 12288
  ushort* Kb0 = smem + 12288;              // 2 bufs x (3 x 128 x 32) = 24576
  float* Mv = (float*)(smem + 12288);      // overlay on K region (dead at end)
  int*   Mi = (int*)(smem + 12288 + 4096); // 4 waves x 32 q x 8

  // bijective XCD swizzle: each XCD owns 2 (v,b) pairs entirely (K L2-pinned)
  int fid = blockIdx.x + 32 * (blockIdx.y + 8 * blockIdx.z);
  int xcd = fid & 7, jj = fid >> 3;        // jj 0..63
  int pair = xcd * 2 + (jj & 1);
  int rt = jj >> 1;                        // 0..31 q row-tile
  int v = pair & 7, b = pair >> 3;

  const long arow0 = (long)b * 1024 + rt * 32;   // q-row base (2048-row space)
  const long brow0 = (long)b * 1024;             // key-row base
  const int vb = v * 128;

  int tid = threadIdx.x;
  int lane = tid & 63, wv = tid >> 6;
  int kg = wv & 3, qg = wv >> 2;       // wave: 32 k-rows x 16 q-cols of tile
  int quad = lane >> 4, l16 = lane & 15;

  // ---- Q prologue: 1536 16B slots, 3 per thread, LDS-linear dest ----
#pragma unroll
  for (int n = 0; n < 3; n++) {
    int base = n * 512 + wv * 64;
    int sl = base + lane;
    int s = sl >> 9, rem = sl & 511;
    int r = rem >> 4, sq = rem & 15;
    int qb = sq ^ (r & 7);                       // inverse swizzle on source
    gload_lds16(qs + (long)s * XPL + (arow0 + r) * 1024 + vb + qb * 8,
                &Qsm[base * 8]);
  }

  // ---- K staging: 1536 slots/buffer, 3 per thread; per-step offset uniform ----
  const ushort* gKp[3]; int ldsKo[3];
#pragma unroll
  for (int n = 0; n < 3; n++) {
    int base = n * 512 + wv * 64;
    int sl = base + lane;
    int s = sl >> 9, rem = sl & 511;
    int c = rem >> 2, sq = rem & 3;
    int qb = sq ^ ((c >> 1) & 3);                // inverse swizzle on source
    gKp[n] = ks + (long)s * XPL + (brow0 + c) * 1024 + vb + qb * 8;
    ldsKo[n] = base * 8;
  }
  auto stageK = [&](int step, int bsel) {
    long off = (long)(step >> 2) * 131072 + (step & 3) * 32;   // uniform
    ushort* Kd = Kb0 + bsel * 12288;
#pragma unroll
    for (int n = 0; n < 3; n++)
      gload_lds16(gKp[n] + off, &Kd[ldsKo[n]]);
  };

  stageK(0, 0);
  __syncthreads();   // drains Q + K step0

  floatx4 acc[2] = {};                 // [i: k 16-group], one q-row group
  float tv[8]; int ti[8];              // per-lane running top-8 (one q-row)
#pragma unroll
  for (int t = 0; t < 8; t++) { tv[t] = -1e30f; ti[t] = 0x7FFFFFFF; }
  float pend[8];                       // previous tile's candidates
  int pbase = 0;

  int buf = 0;
  for (int ct = 0; ct < 8; ct++) {
#pragma unroll
    for (int kk = 0; kk < 4; kk++) {
      int step = ct * 4 + kk;
      if (step < 31) stageK(step + 1, buf ^ 1);

      const ushort* Kc = Kb0 + buf * 12288;
      short8 qf[3], kf[3][2];
#pragma unroll
      for (int s = 0; s < 3; s++) {
        int q = qg * 16 + l16;
        int sqa = (kk * 4 + quad) ^ (q & 7);
        qf[s] = *(const short8*)(&Qsm[s * 4096 + q * 128 + sqa * 8]);
      }
#pragma unroll
      for (int s = 0; s < 3; s++)
#pragma unroll
        for (int i = 0; i < 2; i++) {
          int c = kg * 32 + i * 16 + l16;
          int sqb = quad ^ ((c >> 1) & 3);
          kf[s][i] = *(const short8*)(&Kc[s * 4096 + c * 32 + sqb * 8]);
        }
#pragma unroll
      for (int i = 0; i < 2; i++) {
        // same (kplane,qplane) order as verified: (1,1),(2,0),(0,2),(1,0),(0,1),(0,0)
        acc[i] = __builtin_amdgcn_mfma_f32_16x16x32_bf16(kf[1][i], qf[1], acc[i], 0, 0, 0);
        acc[i] = __builtin_amdgcn_mfma_f32_16x16x32_bf16(kf[2][i], qf[0], acc[i], 0, 0, 0);
        acc[i] = __builtin_amdgcn_mfma_f32_16x16x32_bf16(kf[0][i], qf[2], acc[i], 0, 0, 0);
        acc[i] = __builtin_amdgcn_mfma_f32_16x16x32_bf16(kf[1][i], qf[0], acc[i], 0, 0, 0);
        acc[i] = __builtin_amdgcn_mfma_f32_16x16x32_bf16(kf[0][i], qf[1], acc[i], 0, 0, 0);
        acc[i] = __builtin_amdgcn_mfma_f32_16x16x32_bf16(kf[0][i], qf[0], acc[i], 0, 0, 0);
      }

      // deferred insertion of previous tile's candidates (k-ascending order)
      if (ct > 0) {
        const int t0 = kk * 2, t1 = kk * 2 + 1;
        ins8f(tv, ti, pend[t0], pbase + ((t0 >> 2) << 4) + (quad << 2) + (t0 & 3));
        ins8f(tv, ti, pend[t1], pbase + ((t1 >> 2) << 4) + (quad << 2) + (t1 & 3));
      }
      __syncthreads();   // drains prefetch + guards buf reuse
      buf ^= 1;
    }
    // park this tile's 8 candidates; insert them during next tile's MFMA
#pragma unroll
    for (int i = 0; i < 2; i++)
#pragma unroll
      for (int r = 0; r < 4; r++) {
        pend[i * 4 + r] = acc[i][r];
        acc[i][r] = 0.0f;
      }
    pbase = ct * 128 + kg * 32;
  }
  // drain the final tile's candidates
#pragma unroll
  for (int t = 0; t < 8; t++)
    ins8f(tv, ti, pend[t], pbase + ((t >> 2) << 4) + (quad << 2) + (t & 3));

  // ---- merge across the 4 quad-lanes; quad0 stores per-wave list to LDS ----
  // (K buffers dead: all waves passed the final kk barrier)
  int row = qg * 16 + l16;
  quadmerge_store(tv, ti, Mv, Mi, (kg * 32 + row) * 8, quad);
  __syncthreads();

  // ---- final 4-list merge + softmax, one thread per q-row ----
  if (tid < 32) {
    int q = tid;
    int i0 = 0, i1 = 0, i2 = 0, i3 = 0;
    float pv[8]; int pc[8];
#pragma unroll
    for (int t = 0; t < 8; t++) {
      float v0 = Mv[(0 * 32 + q) * 8 + i0]; int c0 = Mi[(0 * 32 + q) * 8 + i0];
      float v1 = Mv[(1 * 32 + q) * 8 + i1]; int c1 = Mi[(1 * 32 + q) * 8 + i1];
      float v2 = Mv[(2 * 32 + q) * 8 + i2]; int c2 = Mi[(2 * 32 + q) * 8 + i2];
      float v3 = Mv[(3 * 32 + q) * 8 + i3]; int c3 = Mi[(3 * 32 + q) * 8 + i3];
      bool b01 = better(v1, c1, v0, c0);
      float w01v = b01 ? v1 : v0; int w01c = b01 ? c1 : c0; int w01l = b01 ? 1 : 0;
      bool b23 = better(v3, c3, v2, c2);
      float w23v = b23 ? v3 : v2; int w23c = b23 ? c3 : c2; int w23l = b23 ? 3 : 2;
      bool bf_ = better(w23v, w23c, w01v, w01c);
      float wvv = bf_ ? w23v : w01v; int wcc = bf_ ? w23c : w01c;
      int wl = bf_ ? w23l : w01l;
      i0 += (wl == 0); i1 += (wl == 1); i2 += (wl == 2); i3 += (wl == 3);
      pv[t] = wvv; pc[t] = wcc;
    }
    float m = pv[0], sum = 0.f, e[8];
#pragma unroll
    for (int t = 0; t < 8; t++) { e[t] = __expf(pv[t] - m); sum += e[t]; }
    float inv = 1.0f / sum;
    long grow = (long)b * 8192 + v * 1024 + rt * 32 + q;
#pragma unroll
    for (int t = 0; t < 8; t++) {
      wts[grow * 8 + t] = e[t] * inv;
      idxs[grow * 8 + t] = pc[t];
    }
  }
}

// ---------------- gather + weighted sum ----------------
__global__ __launch_bounds__(256) void gather_out_k(const float* __restrict__ src,
                                                    const float* __restrict__ wts,
                                                    const int* __restrict__ idxs,
                                                    float* __restrict__ out) {
  int rowid = blockIdx.x;
  int b = rowid >> 13;
  int tid = threadIdx.x;
  int d4 = tid & 127;
  int w0 = (tid >> 7) << 1;
  const float4* s4 = (const float4*)src + (long)b * (L_SEQ * (DSRC / 4));
  float wt[8]; int id[8];
#pragma unroll
  for (int k = 0; k < 8; k++) {
    wt[k] = wts[(long)rowid * 8 + k];
    id[k] = idxs[(long)rowid * 8 + k];
  }
  float ax = 0, ay = 0, az = 0, aw = 0;
  float bx = 0, by = 0, bz2 = 0, bw = 0;
#pragma unroll
  for (int k = 0; k < 8; k++) {
    int r0 = id[k] + w0 - 1;
    if ((unsigned)r0 < (unsigned)L_SEQ) {
      float4 x = s4[(long)r0 * 128 + d4];
      ax += wt[k] * x.x; ay += wt[k] * x.y; az += wt[k] * x.z; aw += wt[k] * x.w;
    }
    int r1 = r0 + 1;
    if ((unsigned)r1 < (unsigned)L_SEQ) {
      float4 x = s4[(long)r1 * 128 + d4];
      bx += wt[k] * x.x; by += wt[k] * x.y; bz2 += wt[k] * x.z; bw += wt[k] * x.w;
    }
  }
  float4* o4 = (float4*)out + ((long)rowid * 4 + w0) * 128 + d4;
  o4[0] = make_float4(ax, ay, az, aw);
  o4[128] = make_float4(bx, by, bz2, bw);
}

extern "C" void kernel_launch(void* const* d_in, const int* in_sizes, int n_in,
                              void* d_out, int out_size, void* d_ws, size_t ws_size,
                              hipStream_t stream) {
  (void)in_sizes; (void)n_in; (void)out_size; (void)ws_size;
  const float* query  = (const float*)d_in[0];
  const float* key_t  = (const float*)d_in[1];
  const float* source = (const float*)d_in[2];
  const float* wq     = (const float*)d_in[3];
  const float* bq     = (const float*)d_in[4];
  const float* wk     = (const float*)d_in[5];
  const float* bk     = (const float*)d_in[6];

  char* ws = (char*)d_ws;
  // ws layout (bytes), max end 63,963,136 < proven 84,934,656:
  //   0         qs  bf16x3 planes of q (3 x 2048x1024)  12.58 MB  live: proj -> score
  //   12582912  ks  bf16x3 planes of k                  12.58 MB
  //   25165824  wts fp32 (16384x8)                      512 KB
  //   25690112  idxs i32                                512 KB
  //   26214400  xs: 6 bf16 planes (xq,xk)               25.17 MB  dead after proj
  //   51380224  wsp: 6 bf16 planes (wq,wk)              12.58 MB  dead after proj
  //   (scores never materialized in global memory)
  ushort* qs  = (ushort*)(ws);
  ushort* ksp = (ushort*)(ws + 12582912);
  float*  wts = (float*)(ws + 25165824);
  int*    idxs= (int*)(ws + 25690112);
  ushort* xs  = (ushort*)(ws + 26214400);
  ushort* wsp = (ushort*)(ws + 51380224);

  split_inputs_k<<<6144, 256, 0, stream>>>(query, key_t, wq, wk, xs, wsp);
  proj_gemm_k<<<dim3(8, 16, 2), 512, 0, stream>>>(xs, wsp, qs, ksp, bq, bk);
  score_topk_k<<<dim3(32, 8, 2), 512, 0, stream>>>(qs, ksp, wts, idxs);
  gather_out_k<<<16384, 256, 0, stream>>>(source, wts, idxs, (float*)d_out);
}